// Round 8
// baseline (65.329 us; speedup 1.0000x reference)
//
#include <hip/hip_runtime.h>

// Problem dims (fixed by setup_inputs): B=4, S=1024, T=256, H=512, A=256
#define B_ 4
#define S_ 1024
#define T_ 256
#define H_ 512
#define A_ 256

typedef __attribute__((ext_vector_type(8))) short short8;   // 8 bf16 = 4 VGPR
typedef __attribute__((ext_vector_type(4))) float f32x4;    // MFMA acc

__device__ __forceinline__ float ex2(float x)   { return __builtin_amdgcn_exp2f(x); }
__device__ __forceinline__ float rcpf_(float x) { return __builtin_amdgcn_rcpf(x); }

#define K2F 2.8853900817779268f     // 2*log2(e): exp(2x) = exp2(K2F*x)

// fp32 -> bf16 split: x ~= hi + lo (both bf16, RNE).
__device__ __forceinline__ void split_bf16(float x, unsigned short& h, unsigned short& l)
{
    unsigned u = __float_as_uint(x);
    unsigned r = (u + 0x7FFFu + ((u >> 16) & 1u)) >> 16;
    h = (unsigned short)r;
    float hf = __uint_as_float(r << 16);
    float lo = x - hf;                       // exact in fp32
    unsigned u2 = __float_as_uint(lo);
    l = (unsigned short)((u2 + 0x7FFFu + ((u2 >> 16) & 1u)) >> 16);
}

// ---------------------------------------------------------------------------
// Kernel 0: transpose + bf16-split W matrices.  W[k][a] -> WT_hi/lo[a][k].
// ---------------------------------------------------------------------------
__global__ __launch_bounds__(256)
void prep_w(const float* __restrict__ Wh, const float* __restrict__ Wsm,
            unsigned short* __restrict__ WhTh, unsigned short* __restrict__ WhTl,
            unsigned short* __restrict__ WsTh, unsigned short* __restrict__ WsTl)
{
    __shared__ float lds[32][36];
    const int tid = threadIdx.x, bid = blockIdx.x;
    const int mat = bid >> 7, rem = bid & 127;
    const int k0 = (rem & 15) * 32, a0 = (rem >> 4) * 32;
    const float* W = mat ? Wsm : Wh;
    unsigned short* Oh = mat ? WsTh : WhTh;
    unsigned short* Ol = mat ? WsTl : WhTl;

    {
        int kl = tid >> 3, a4 = (tid & 7) * 4;
        float4 v = *(const float4*)&W[(size_t)(k0 + kl) * A_ + a0 + a4];
        lds[kl][a4] = v.x; lds[kl][a4 + 1] = v.y; lds[kl][a4 + 2] = v.z; lds[kl][a4 + 3] = v.w;
    }
    __syncthreads();
    {
        int al = tid >> 3, k4 = (tid & 7) * 4;
        unsigned short h[4], l[4];
        #pragma unroll
        for (int i = 0; i < 4; ++i) split_bf16(lds[k4 + i][al], h[i], l[i]);
        size_t o = (size_t)(a0 + al) * H_ + k0 + k4;
        *(ushort4*)&Oh[o] = make_ushort4(h[0], h[1], h[2], h[3]);
        *(ushort4*)&Ol[o] = make_ushort4(l[0], l[1], l[2], l[3]);
    }
}

// ---------------------------------------------------------------------------
// Kernel 1: split-bf16 MFMA GEMM + exp epilogue. 64x32 tiles -> 640 blocks
// (2.5 blk/CU vs round-7's 1.25 -- the gemm was occupancy-starved).
//   blocks [0,512):   E[b][a][s] = exp(2*(enc@Wh + bh))  (transposed store)
//   blocks [512,640): D[m][a]    = exp(2*(dec@Ws + bs))  (row-major store)
// 4 waves (wm 0..1 x wn 0..1), each wave 32 rows x 16 cols (2 m-frags).
// ---------------------------------------------------------------------------
__global__ __launch_bounds__(256)
void gemm_mfma(const float* __restrict__ enc, const float* __restrict__ dec,
               const unsigned short* __restrict__ WhTh, const unsigned short* __restrict__ WhTl,
               const unsigned short* __restrict__ WsTh, const unsigned short* __restrict__ WsTl,
               const float* __restrict__ bh, const float* __restrict__ bs,
               float* __restrict__ Ebuf, float* __restrict__ Dbuf)
{
    __shared__ short smem[6144];          // 12 KB: Ah 2048 | Al 2048 | Bh 1024 | Bl 1024
    short* Ah = smem;
    short* Al = smem + 2048;
    short* Bh = smem + 4096;
    short* Bl = smem + 5120;

    const int tid = threadIdx.x, bid = blockIdx.x;
    const bool isE = bid < 512;
    int mb, nb;
    const float* Ag; const unsigned short* WTh; const unsigned short* WTl; const float* bias;
    if (isE) { mb = (bid & 63) * 64; nb = (bid >> 6) * 32; Ag = enc; WTh = WhTh; WTl = WhTl; bias = bh; }
    else { int b2 = bid - 512; mb = (b2 & 15) * 64; nb = (b2 >> 4) * 32; Ag = dec; WTh = WsTh; WTl = WsTl; bias = bs; }

    // A staging: 256 thr, m_l=tid>>2 (0..63), q=tid&3 (8-k chunk)
    const int m_l = tid >> 2, q = tid & 3;
    const size_t arow = (size_t)(mb + m_l) * H_ + 8 * q;
    const int woffA = ((m_l >> 4) * 64 + (m_l & 15) + 16 * q) * 8;
    // B staging: threads 0..127, a_l=tid>>2 (0..31)
    const bool doB = tid < 128;
    const size_t brow = (size_t)(nb + (m_l & 31)) * H_ + 8 * q;
    const int woffB = (((m_l & 31) >> 4) * 64 + (m_l & 15) + 16 * q) * 8;

    const int wave = tid >> 6, lane = tid & 63;
    const int wm = wave >> 1, wn = wave & 1;
    const int roffA = (2 * wm) * 512 + lane * 8;          // +mf*512
    const int roffB = wn * 512 + lane * 8;

    const int cl = lane & 15, rg = lane >> 4;
    const float bias0 = bias[nb + wn * 16 + cl];

    f32x4 acc[2] = {};

    float4 aA = *(const float4*)&Ag[arow];
    float4 aB = *(const float4*)&Ag[arow + 4];
    short8 bHv, bLv;
    if (doB) {
        bHv = *(const short8*)&WTh[brow];
        bLv = *(const short8*)&WTl[brow];
    }

    for (int it = 0; it < 16; ++it) {
        __syncthreads();
        {
            float xs[8] = {aA.x, aA.y, aA.z, aA.w, aB.x, aB.y, aB.z, aB.w};
            short8 hv, lv;
            #pragma unroll
            for (int j = 0; j < 8; ++j) {
                unsigned short h, l; split_bf16(xs[j], h, l);
                hv[j] = (short)h; lv[j] = (short)l;
            }
            *(short8*)&Ah[woffA] = hv;
            *(short8*)&Al[woffA] = lv;
            if (doB) {
                *(short8*)&Bh[woffB] = bHv;
                *(short8*)&Bl[woffB] = bLv;
            }
        }
        if (it < 15) {
            int kn = (it + 1) * 32;
            aA  = *(const float4*)&Ag[arow + kn];
            aB  = *(const float4*)&Ag[arow + kn + 4];
            if (doB) {
                bHv = *(const short8*)&WTh[brow + kn];
                bLv = *(const short8*)&WTl[brow + kn];
            }
        }
        __syncthreads();
        short8 fBh = *(short8*)&Bh[roffB];
        short8 fBl = *(short8*)&Bl[roffB];
        #pragma unroll
        for (int mf = 0; mf < 2; ++mf) {
            short8 fAh = *(short8*)&Ah[roffA + mf * 512];
            short8 fAl = *(short8*)&Al[roffA + mf * 512];
            acc[mf] = __builtin_amdgcn_mfma_f32_16x16x32_bf16(fAh, fBh, acc[mf], 0, 0, 0);
            acc[mf] = __builtin_amdgcn_mfma_f32_16x16x32_bf16(fAh, fBl, acc[mf], 0, 0, 0);
            acc[mf] = __builtin_amdgcn_mfma_f32_16x16x32_bf16(fAl, fBh, acc[mf], 0, 0, 0);
        }
    }

    #pragma unroll
    for (int mf = 0; mf < 2; ++mf) {
        const int mg = mb + wm * 32 + mf * 16 + rg * 4;
        const int a = nb + wn * 16 + cl;
        f32x4 ac = acc[mf];
        float4 st;
        st.x = ex2((ac[0] + bias0) * K2F);
        st.y = ex2((ac[1] + bias0) * K2F);
        st.z = ex2((ac[2] + bias0) * K2F);
        st.w = ex2((ac[3] + bias0) * K2F);
        if (isE) {
            const int b = mg >> 10, s = mg & 1023;
            *(float4*)&Ebuf[(((size_t)b * A_ + a) << 10) + s] = st;
        } else {
            Dbuf[(size_t)(mg + 0) * A_ + a] = st.x;
            Dbuf[(size_t)(mg + 1) * A_ + a] = st.y;
            Dbuf[(size_t)(mg + 2) * A_ + a] = st.z;
            Dbuf[(size_t)(mg + 3) * A_ + a] = st.w;
        }
    }
}

// ---------------------------------------------------------------------------
// Kernel 2 (primary): 16-way a-split partial scores with SGPR-resident D/W.
// block = (b, 4 t-rows, a-chunk of 16); 4096 blocks (16/CU), 512 thr x 2 s.
// The 80-float D/W working set is loaded via 5 uniform s_load_dwordx16 into
// SGPRs up front; every inner VALU op reads d/w as its single SGPR operand.
// NO LDS, NO per-iter d/w memory traffic (round-7 profile: the LDS broadcast
// reads alone cost ~12.8us/CU -- broadcast still moves 16Bx64 lanes).
// P[h][b*T+t][s] partials in fp32; merge kernel applies exp2/normalize.
// ---------------------------------------------------------------------------
#define GROUP4(e0, e1, e2, e3, A0)                                           \
    _Pragma("unroll")                                                        \
    for (int t = 0; t < 4; ++t) {                                            \
        { float q0 = fmaf(e0.x, ds[t][(A0)],     1.0f);                      \
          float q1 = fmaf(e1.x, ds[t][(A0) + 1], 1.0f);                      \
          float q2 = fmaf(e2.x, ds[t][(A0) + 2], 1.0f);                      \
          float q3 = fmaf(e3.x, ds[t][(A0) + 3], 1.0f);                      \
          float q01 = q0 * q1, q23 = q2 * q3;                                \
          float n1 = fmaf(wv[(A0)], q1, wv[(A0) + 1] * q0);                  \
          float n2 = fmaf(wv[(A0) + 2], q3, wv[(A0) + 3] * q2);              \
          float num = fmaf(n1, q23, n2 * q01);                               \
          accx[t] = fmaf(num, rcpf_(q01 * q23), accx[t]); }                  \
        { float q0 = fmaf(e0.y, ds[t][(A0)],     1.0f);                      \
          float q1 = fmaf(e1.y, ds[t][(A0) + 1], 1.0f);                      \
          float q2 = fmaf(e2.y, ds[t][(A0) + 2], 1.0f);                      \
          float q3 = fmaf(e3.y, ds[t][(A0) + 3], 1.0f);                      \
          float q01 = q0 * q1, q23 = q2 * q3;                                \
          float n1 = fmaf(wv[(A0)], q1, wv[(A0) + 1] * q0);                  \
          float n2 = fmaf(wv[(A0) + 2], q3, wv[(A0) + 3] * q2);              \
          float num = fmaf(n1, q23, n2 * q01);                               \
          accy[t] = fmaf(num, rcpf_(q01 * q23), accy[t]); }                  \
    }

__global__ __launch_bounds__(512)
void score_partial16(const float* __restrict__ E, const float* __restrict__ D,
                     const float* __restrict__ Wv, float* __restrict__ P)
{
    const int tid = threadIdx.x;
    const int bid = blockIdx.x;               // 4096
    const int b   = bid >> 10;
    const int rem = bid & 1023;
    const int h   = rem & 15;
    const int t0  = (rem >> 4) * 4;
    const int abase = h * 16;

    // uniform scalar loads -> SGPR-resident D slice + W chunk (80 floats)
    float ds[4][16], wv[16];
    #pragma unroll
    for (int t = 0; t < 4; ++t)
        #pragma unroll
        for (int i = 0; i < 16; ++i)
            ds[t][i] = D[((size_t)b * T_ + t0 + t) * A_ + abase + i];
    #pragma unroll
    for (int i = 0; i < 16; ++i) wv[i] = Wv[abase + i];

    const int s0 = tid << 1;
    const float* Eb = E + ((size_t)b * A_ + abase) * S_ + s0;

    float accx[4] = {}, accy[4] = {};
    float2 ev[8];

    #pragma unroll
    for (int j = 0; j < 8; ++j) ev[j] = *(const float2*)&Eb[(size_t)j * S_];
    GROUP4(ev[0], ev[1], ev[2], ev[3], 0);
    GROUP4(ev[4], ev[5], ev[6], ev[7], 4);
    #pragma unroll
    for (int j = 0; j < 8; ++j) ev[j] = *(const float2*)&Eb[(size_t)(8 + j) * S_];
    GROUP4(ev[0], ev[1], ev[2], ev[3], 8);
    GROUP4(ev[4], ev[5], ev[6], ev[7], 12);

    #pragma unroll
    for (int t = 0; t < 4; ++t) {
        float2 o; o.x = accx[t]; o.y = accy[t];
        *(float2*)&P[((size_t)h * (B_ * T_) + (size_t)b * T_ + t0 + t) * S_ + s0] = o;
    }
}

// ---------------------------------------------------------------------------
// Kernel 3 (primary): merge 16 partials + softmax. block = one (b,t) row.
// score' = -2*sum_h P[h]; softmax without max-subtraction (|score'| <= ~26).
// ---------------------------------------------------------------------------
__global__ __launch_bounds__(256)
void merge_softmax16(const float* __restrict__ P, float* __restrict__ outp)
{
    const int row = blockIdx.x;               // b*T + t
    const int tid = threadIdx.x;
    const int lane = tid & 63, wid = tid >> 6;
    __shared__ float red[4];

    const int s4 = tid << 2;
    float4 a = *(const float4*)&P[(size_t)row * S_ + s4];
    #pragma unroll
    for (int hh = 1; hh < 16; ++hh) {
        float4 c = *(const float4*)&P[((size_t)hh * (B_ * T_) + row) * S_ + s4];
        a.x += c.x; a.y += c.y; a.z += c.z; a.w += c.w;
    }
    float e0 = ex2(a.x * -K2F);
    float e1 = ex2(a.y * -K2F);
    float e2 = ex2(a.z * -K2F);
    float e3 = ex2(a.w * -K2F);

    float ssum = (e0 + e1) + (e2 + e3);
    #pragma unroll
    for (int off = 32; off > 0; off >>= 1) ssum += __shfl_xor(ssum, off, 64);
    if (lane == 0) red[wid] = ssum;
    __syncthreads();
    float tot = (red[0] + red[1]) + (red[2] + red[3]);
    float inv = 1.0f / tot;

    *(float4*)&outp[(size_t)row * S_ + s4] = make_float4(e0 * inv, e1 * inv, e2 * inv, e3 * inv);
}

// ---------------------------------------------------------------------------
// Fallback kernels (round-7, known-good) for small ws.
// ---------------------------------------------------------------------------
template<int AS>
__global__ __launch_bounds__(512)
void score_partial(const float* __restrict__ E, const float* __restrict__ D,
                   const float* __restrict__ Wv,
                   float* __restrict__ P0, float* __restrict__ P1,
                   float* __restrict__ P2, float* __restrict__ P3)
{
    constexpr int ABLK = 256 / AS;
    constexpr int NG   = ABLK / 4;

    const int tid = threadIdx.x;
    const int bid = blockIdx.x;
    const int b   = bid / (64 * AS);
    const int rem = bid % (64 * AS);
    const int h   = rem & (AS - 1);
    const int t0  = (rem / AS) * 4;
    const int abase = h * ABLK;

    __shared__ float Dsh[4][ABLK];
    __shared__ float Wsh[ABLK];

    if (tid < ABLK) {
        int r = tid / (ABLK / 4), c4 = (tid % (ABLK / 4)) << 2;
        *(float4*)&Dsh[r][c4] = *(const float4*)&D[((size_t)b * T_ + t0 + r) * A_ + abase + c4];
    } else if (tid < ABLK + ABLK / 4) {
        int c4 = (tid - ABLK) << 2;
        *(float4*)&Wsh[c4] = *(const float4*)&Wv[abase + c4];
    }
    __syncthreads();

    const int s0 = tid << 1;
    const float* Eb = E + ((size_t)b * A_ + abase) * S_ + s0;

    float accx[4] = {}, accy[4] = {};
    float2 evA[4], evB[4];

    #pragma unroll
    for (int j = 0; j < 4; ++j) evA[j] = *(const float2*)&Eb[(size_t)j * S_];

    auto compute = [&](const float2* ev, int g) {
        float4 w = *(const float4*)&Wsh[g * 4];
        #pragma unroll
        for (int t = 0; t < 4; ++t) {
            float4 d = *(const float4*)&Dsh[t][g * 4];
            {
                float q0 = fmaf(ev[0].x, d.x, 1.0f);
                float q1 = fmaf(ev[1].x, d.y, 1.0f);
                float q2 = fmaf(ev[2].x, d.z, 1.0f);
                float q3 = fmaf(ev[3].x, d.w, 1.0f);
                float q01 = q0 * q1, q23 = q2 * q3;
                float n1 = fmaf(w.x, q1, w.y * q0);
                float n2 = fmaf(w.z, q3, w.w * q2);
                float num = fmaf(n1, q23, n2 * q01);
                accx[t] = fmaf(num, rcpf_(q01 * q23), accx[t]);
            }
            {
                float q0 = fmaf(ev[0].y, d.x, 1.0f);
                float q1 = fmaf(ev[1].y, d.y, 1.0f);
                float q2 = fmaf(ev[2].y, d.z, 1.0f);
                float q3 = fmaf(ev[3].y, d.w, 1.0f);
                float q01 = q0 * q1, q23 = q2 * q3;
                float n1 = fmaf(w.x, q1, w.y * q0);
                float n2 = fmaf(w.z, q3, w.w * q2);
                float num = fmaf(n1, q23, n2 * q01);
                accy[t] = fmaf(num, rcpf_(q01 * q23), accy[t]);
            }
        }
    };

    for (int g = 0; g < NG; g += 2) {
        #pragma unroll
        for (int j = 0; j < 4; ++j) evB[j] = *(const float2*)&Eb[(size_t)((g + 1) * 4 + j) * S_];
        compute(evA, g);
        if (g + 2 < NG) {
            #pragma unroll
            for (int j = 0; j < 4; ++j) evA[j] = *(const float2*)&Eb[(size_t)((g + 2) * 4 + j) * S_];
        }
        compute(evB, g + 1);
    }

    float* Pd = (h == 0) ? P0 : (h == 1) ? P1 : (h == 2) ? P2 : P3;
    #pragma unroll
    for (int t = 0; t < 4; ++t) {
        float2 o; o.x = accx[t]; o.y = accy[t];
        *(float2*)&Pd[((size_t)b * T_ + t0 + t) * S_ + s0] = o;
    }
}

template<int NP>
__global__ __launch_bounds__(256)
void merge_softmax(const float* __restrict__ P1, const float* __restrict__ P2,
                   const float* __restrict__ P3, float* __restrict__ outp)
{
    const int row = blockIdx.x;
    const int tid = threadIdx.x;
    const int lane = tid & 63, wid = tid >> 6;
    __shared__ float red[4];

    float* o = outp + (size_t)row * S_;
    const int s4 = tid << 2;

    float4 a = *(const float4*)&o[s4];
    {
        float4 c = *(const float4*)&P1[(size_t)row * S_ + s4];
        a.x += c.x; a.y += c.y; a.z += c.z; a.w += c.w;
    }
    if (NP >= 4) {
        float4 c = *(const float4*)&P2[(size_t)row * S_ + s4];
        a.x += c.x; a.y += c.y; a.z += c.z; a.w += c.w;
        float4 e = *(const float4*)&P3[(size_t)row * S_ + s4];
        a.x += e.x; a.y += e.y; a.z += e.z; a.w += e.w;
    }
    float e0 = ex2(a.x * -K2F);
    float e1 = ex2(a.y * -K2F);
    float e2 = ex2(a.z * -K2F);
    float e3 = ex2(a.w * -K2F);

    float ssum = (e0 + e1) + (e2 + e3);
    #pragma unroll
    for (int off = 32; off > 0; off >>= 1) ssum += __shfl_xor(ssum, off, 64);
    if (lane == 0) red[wid] = ssum;
    __syncthreads();
    float tot = (red[0] + red[1]) + (red[2] + red[3]);
    float inv = 1.0f / tot;

    *(float4*)&o[s4] = make_float4(e0 * inv, e1 * inv, e2 * inv, e3 * inv);
}

// ---------------------------------------------------------------------------
extern "C" void kernel_launch(void* const* d_in, const int* in_sizes, int n_in,
                              void* d_out, int out_size, void* d_ws, size_t ws_size,
                              hipStream_t stream)
{
    const float* enc = (const float*)d_in[0];
    const float* dec = (const float*)d_in[1];
    const float* Wh  = (const float*)d_in[2];
    const float* bh  = (const float*)d_in[3];
    const float* Wsm = (const float*)d_in[4];
    const float* bs  = (const float*)d_in[5];
    const float* Wv  = (const float*)d_in[6];
    // d_in[7] (bv) intentionally unused: softmax is shift-invariant.

    char* ws = (char*)d_ws;
    float* Ebuf = (float*)ws;                                // [0,4MB)
    float* Dbuf = (float*)(ws + (4 << 20));                  // [4,5MB)
    unsigned short* wt = (unsigned short*)(ws + (5 << 20));  // [5,6MB)
    unsigned short* WhTh = wt;
    unsigned short* WhTl = wt + 131072;
    unsigned short* WsTh = wt + 262144;
    unsigned short* WsTl = wt + 393216;

    prep_w<<<256, 256, 0, stream>>>(Wh, Wsm, WhTh, WhTl, WsTh, WsTl);
    gemm_mfma<<<640, 256, 0, stream>>>(enc, dec, WhTh, WhTl, WsTh, WsTl,
                                       bh, bs, Ebuf, Dbuf);

    if (ws_size >= (size_t)(72 << 20)) {
        float* P16 = (float*)(ws + (6 << 20));               // [6,70MB): 16 x 4MB
        score_partial16<<<4096, 512, 0, stream>>>(Ebuf, Dbuf, Wv, P16);
        merge_softmax16<<<B_ * T_, 256, 0, stream>>>(P16, (float*)d_out);
    } else if (ws_size >= (size_t)(18 << 20)) {
        float* P1 = (float*)(ws + (6 << 20));
        float* P2 = (float*)(ws + (10 << 20));
        float* P3 = (float*)(ws + (14 << 20));
        float* P0 = (float*)d_out;
        score_partial<4><<<B_ * 256, 512, 0, stream>>>(Ebuf, Dbuf, Wv, P0, P1, P2, P3);
        merge_softmax<4><<<B_ * T_, 256, 0, stream>>>(P1, P2, P3, (float*)d_out);
    } else {
        float* P1 = (float*)(ws + (6 << 20));
        float* P0 = (float*)d_out;
        score_partial<2><<<B_ * 128, 512, 0, stream>>>(Ebuf, Dbuf, Wv, P0, P1, nullptr, nullptr);
        merge_softmax<2><<<B_ * T_, 256, 0, stream>>>(P1, nullptr, nullptr, (float*)d_out);
    }
}

// Round 9
// 54.909 us; speedup vs baseline: 1.1898x; 1.1898x over previous
//
#include <hip/hip_runtime.h>

// Problem dims (fixed by setup_inputs): B=4, S=1024, T=256, H=512, A=256
#define B_ 4
#define S_ 1024
#define T_ 256
#define H_ 512
#define A_ 256

typedef __attribute__((ext_vector_type(8))) short short8;   // 8 bf16 = 4 VGPR
typedef __attribute__((ext_vector_type(4))) float f32x4;    // MFMA acc / float4
typedef __attribute__((ext_vector_type(2))) float f32x2;    // v_pk_*_f32 pair

__device__ __forceinline__ float ex2(float x)   { return __builtin_amdgcn_exp2f(x); }
__device__ __forceinline__ float rcpf_(float x) { return __builtin_amdgcn_rcpf(x); }
__device__ __forceinline__ f32x2 fma2(f32x2 a, f32x2 b, f32x2 c) {
    return __builtin_elementwise_fma(a, b, c);
}
__device__ __forceinline__ f32x2 lo2(f32x4 v) { return __builtin_shufflevector(v, v, 0, 1); }
__device__ __forceinline__ f32x2 hi2(f32x4 v) { return __builtin_shufflevector(v, v, 2, 3); }

#define K2F 2.8853900817779268f     // 2*log2(e): exp(2x) = exp2(K2F*x)

// fp32 -> bf16 split: x ~= hi + lo (both bf16, RNE).
__device__ __forceinline__ void split_bf16(float x, unsigned short& h, unsigned short& l)
{
    unsigned u = __float_as_uint(x);
    unsigned r = (u + 0x7FFFu + ((u >> 16) & 1u)) >> 16;
    h = (unsigned short)r;
    float hf = __uint_as_float(r << 16);
    float lo = x - hf;                       // exact in fp32
    unsigned u2 = __float_as_uint(lo);
    l = (unsigned short)((u2 + 0x7FFFu + ((u2 >> 16) & 1u)) >> 16);
}

// ---------------------------------------------------------------------------
// Kernel 0: transpose + bf16-split W matrices.  W[k][a] -> WT_hi/lo[a][k].
// ---------------------------------------------------------------------------
__global__ __launch_bounds__(256)
void prep_w(const float* __restrict__ Wh, const float* __restrict__ Wsm,
            unsigned short* __restrict__ WhTh, unsigned short* __restrict__ WhTl,
            unsigned short* __restrict__ WsTh, unsigned short* __restrict__ WsTl)
{
    __shared__ float lds[32][36];
    const int tid = threadIdx.x, bid = blockIdx.x;
    const int mat = bid >> 7, rem = bid & 127;
    const int k0 = (rem & 15) * 32, a0 = (rem >> 4) * 32;
    const float* W = mat ? Wsm : Wh;
    unsigned short* Oh = mat ? WsTh : WhTh;
    unsigned short* Ol = mat ? WsTl : WhTl;

    {
        int kl = tid >> 3, a4 = (tid & 7) * 4;
        float4 v = *(const float4*)&W[(size_t)(k0 + kl) * A_ + a0 + a4];
        lds[kl][a4] = v.x; lds[kl][a4 + 1] = v.y; lds[kl][a4 + 2] = v.z; lds[kl][a4 + 3] = v.w;
    }
    __syncthreads();
    {
        int al = tid >> 3, k4 = (tid & 7) * 4;
        unsigned short h[4], l[4];
        #pragma unroll
        for (int i = 0; i < 4; ++i) split_bf16(lds[k4 + i][al], h[i], l[i]);
        size_t o = (size_t)(a0 + al) * H_ + k0 + k4;
        *(ushort4*)&Oh[o] = make_ushort4(h[0], h[1], h[2], h[3]);
        *(ushort4*)&Ol[o] = make_ushort4(l[0], l[1], l[2], l[3]);
    }
}

// ---------------------------------------------------------------------------
// Kernel 1: split-bf16 MFMA GEMM + exp epilogue (round-7 version, the one in
// the measured-best 56.1us config).
//   blocks [0,256):   E[b][a][s] = exp(2*(enc@Wh + bh))  (transposed store)
//   blocks [256,320): D[m][a]    = exp(2*(dec@Ws + bs))  (row-major store)
// ---------------------------------------------------------------------------
__global__ __launch_bounds__(256)
void gemm_mfma(const float* __restrict__ enc, const float* __restrict__ dec,
               const unsigned short* __restrict__ WhTh, const unsigned short* __restrict__ WhTl,
               const unsigned short* __restrict__ WsTh, const unsigned short* __restrict__ WsTl,
               const float* __restrict__ bh, const float* __restrict__ bs,
               float* __restrict__ Ebuf, float* __restrict__ Dbuf)
{
    __shared__ short smem[8192];          // 16 KB: Ahi|Alo|Bhi|Blo, 4KB each
    short* Ah = smem;
    short* Al = smem + 2048;
    short* Bh = smem + 4096;
    short* Bl = smem + 6144;

    const int tid = threadIdx.x, bid = blockIdx.x;
    const bool isE = bid < 256;
    int mb, nb;
    const float* Ag; const unsigned short* WTh; const unsigned short* WTl; const float* bias;
    if (isE) { mb = (bid & 63) * 64; nb = (bid >> 6) * 64; Ag = enc; WTh = WhTh; WTl = WhTl; bias = bh; }
    else { int b2 = bid - 256; mb = (b2 & 15) * 64; nb = (b2 >> 4) * 64; Ag = dec; WTh = WsTh; WTl = WsTl; bias = bs; }

    const int m_l = tid >> 2, q = tid & 3;
    const size_t arow = (size_t)(mb + m_l) * H_ + 8 * q;
    const size_t brow = (size_t)(nb + m_l) * H_ + 8 * q;
    const int woff = ((m_l >> 4) * 64 + (m_l & 15) + 16 * q) * 8;

    const int wave = tid >> 6, lane = tid & 63;
    const int wm = wave >> 1, wn = wave & 1;
    const int roffA = (2 * wm) * 512 + lane * 8;
    const int roffB = (2 * wn) * 512 + lane * 8;

    const int cl = lane & 15, rg = lane >> 4;
    const float bias0 = bias[nb + wn * 32 + cl];
    const float bias1 = bias[nb + wn * 32 + 16 + cl];

    f32x4 acc[2][2] = {};

    float4 aA = *(const float4*)&Ag[arow];
    float4 aB = *(const float4*)&Ag[arow + 4];
    short8 bHv = *(const short8*)&WTh[brow];
    short8 bLv = *(const short8*)&WTl[brow];

    for (int it = 0; it < 16; ++it) {
        __syncthreads();
        {
            float xs[8] = {aA.x, aA.y, aA.z, aA.w, aB.x, aB.y, aB.z, aB.w};
            short8 hv, lv;
            #pragma unroll
            for (int j = 0; j < 8; ++j) {
                unsigned short h, l; split_bf16(xs[j], h, l);
                hv[j] = (short)h; lv[j] = (short)l;
            }
            *(short8*)&Ah[woff] = hv;
            *(short8*)&Al[woff] = lv;
            *(short8*)&Bh[woff] = bHv;
            *(short8*)&Bl[woff] = bLv;
        }
        if (it < 15) {
            int kn = (it + 1) * 32;
            aA  = *(const float4*)&Ag[arow + kn];
            aB  = *(const float4*)&Ag[arow + kn + 4];
            bHv = *(const short8*)&WTh[brow + kn];
            bLv = *(const short8*)&WTl[brow + kn];
        }
        __syncthreads();
        short8 fAh0 = *(short8*)&Ah[roffA], fAh1 = *(short8*)&Ah[roffA + 512];
        short8 fAl0 = *(short8*)&Al[roffA], fAl1 = *(short8*)&Al[roffA + 512];
        short8 fBh0 = *(short8*)&Bh[roffB], fBh1 = *(short8*)&Bh[roffB + 512];
        short8 fBl0 = *(short8*)&Bl[roffB], fBl1 = *(short8*)&Bl[roffB + 512];
        acc[0][0] = __builtin_amdgcn_mfma_f32_16x16x32_bf16(fAh0, fBh0, acc[0][0], 0, 0, 0);
        acc[0][0] = __builtin_amdgcn_mfma_f32_16x16x32_bf16(fAh0, fBl0, acc[0][0], 0, 0, 0);
        acc[0][0] = __builtin_amdgcn_mfma_f32_16x16x32_bf16(fAl0, fBh0, acc[0][0], 0, 0, 0);
        acc[0][1] = __builtin_amdgcn_mfma_f32_16x16x32_bf16(fAh0, fBh1, acc[0][1], 0, 0, 0);
        acc[0][1] = __builtin_amdgcn_mfma_f32_16x16x32_bf16(fAh0, fBl1, acc[0][1], 0, 0, 0);
        acc[0][1] = __builtin_amdgcn_mfma_f32_16x16x32_bf16(fAl0, fBh1, acc[0][1], 0, 0, 0);
        acc[1][0] = __builtin_amdgcn_mfma_f32_16x16x32_bf16(fAh1, fBh0, acc[1][0], 0, 0, 0);
        acc[1][0] = __builtin_amdgcn_mfma_f32_16x16x32_bf16(fAh1, fBl0, acc[1][0], 0, 0, 0);
        acc[1][0] = __builtin_amdgcn_mfma_f32_16x16x32_bf16(fAl1, fBh0, acc[1][0], 0, 0, 0);
        acc[1][1] = __builtin_amdgcn_mfma_f32_16x16x32_bf16(fAh1, fBh1, acc[1][1], 0, 0, 0);
        acc[1][1] = __builtin_amdgcn_mfma_f32_16x16x32_bf16(fAh1, fBl1, acc[1][1], 0, 0, 0);
        acc[1][1] = __builtin_amdgcn_mfma_f32_16x16x32_bf16(fAl1, fBh1, acc[1][1], 0, 0, 0);
    }

    #pragma unroll
    for (int mf = 0; mf < 2; ++mf) {
        const int mg = mb + wm * 32 + mf * 16 + rg * 4;
        #pragma unroll
        for (int nf = 0; nf < 2; ++nf) {
            const int a = nb + wn * 32 + nf * 16 + cl;
            const float bb = nf ? bias1 : bias0;
            f32x4 ac = acc[mf][nf];
            float4 st;
            st.x = ex2((ac[0] + bb) * K2F);
            st.y = ex2((ac[1] + bb) * K2F);
            st.z = ex2((ac[2] + bb) * K2F);
            st.w = ex2((ac[3] + bb) * K2F);
            if (isE) {
                const int b = mg >> 10, s = mg & 1023;
                *(float4*)&Ebuf[(((size_t)b * A_ + a) << 10) + s] = st;
            } else {
                Dbuf[(size_t)(mg + 0) * A_ + a] = st.x;
                Dbuf[(size_t)(mg + 1) * A_ + a] = st.y;
                Dbuf[(size_t)(mg + 2) * A_ + a] = st.z;
                Dbuf[(size_t)(mg + 3) * A_ + a] = st.w;
            }
        }
    }
}

// ---------------------------------------------------------------------------
// Kernel 2 (primary): packed-fp32 partial scores, AS=4 a-split.
// block = (b, 4 t-rows, 64-a chunk); 1024 blocks x 256 thr x 4 s-cols.
// P[t][s] = sum_a Wv[a] / (E[b,a,s]*D[b,t,a] + 1), 4a share one rcp.
// KEY: D and Wv stored PRE-SPLATTED in LDS ({d,d} pairs) so one uniform
// ds_read_b128 returns {d0,d0,d1,d1} = two ready v_pk_fma_f32 operands --
// zero splat movs (round-6's failure mode). Math on f32x2 across the
// thread's s-pairs -> 14 pk-ops + 2 rcp per 4a*1t*2s = 1.75 VALU/elem,
// half the scalar issue floor. E float4 loads double-buffered.
// ---------------------------------------------------------------------------
__global__ __launch_bounds__(256)
void score_partial_pk(const float* __restrict__ E, const float* __restrict__ D,
                      const float* __restrict__ Wv,
                      float* __restrict__ P0, float* __restrict__ P1,
                      float* __restrict__ P2, float* __restrict__ P3)
{
    const int tid = threadIdx.x;
    const int bid = blockIdx.x;                // 1024
    const int b   = bid >> 8;
    const int rem = bid & 255;
    const int h   = rem & 3;
    const int t0  = (rem >> 2) * 4;
    const int abase = h * 64;

    __shared__ float Dsh[4][64][2];            // pre-splatted {d,d}
    __shared__ float Wsh[64][2];               // pre-splatted {w,w}

    {
        int t = tid >> 6, a = tid & 63;
        float dv = D[((size_t)b * T_ + t0 + t) * A_ + abase + a];
        Dsh[t][a][0] = dv; Dsh[t][a][1] = dv;
        if (tid < 64) {
            float wv_ = Wv[abase + tid];
            Wsh[tid][0] = wv_; Wsh[tid][1] = wv_;
        }
    }
    __syncthreads();

    const int s0 = tid << 2;                   // 4 adjacent s columns
    const float* Eb = E + ((size_t)b * A_ + abase) * S_ + s0;

    f32x2 acc[4][2] = {};                      // [t][s-pair]
    f32x4 eA[4], eB[4];

    #pragma unroll
    for (int j = 0; j < 4; ++j) eA[j] = *(const f32x4*)&Eb[(size_t)j * S_];

    const f32x2 one = {1.0f, 1.0f};

    auto compute = [&](const f32x4* ev, int g) {
        f32x2 eL[4], eH[4];
        #pragma unroll
        for (int j = 0; j < 4; ++j) { eL[j] = lo2(ev[j]); eH[j] = hi2(ev[j]); }
        f32x4 w01 = *(const f32x4*)&Wsh[g * 4][0];       // {w0,w0,w1,w1}
        f32x4 w23 = *(const f32x4*)&Wsh[g * 4 + 2][0];   // {w2,w2,w3,w3}
        f32x2 w0s = lo2(w01), w1s = hi2(w01), w2s = lo2(w23), w3s = hi2(w23);
        #pragma unroll
        for (int t = 0; t < 4; ++t) {
            f32x4 d01 = *(const f32x4*)&Dsh[t][g * 4][0];
            f32x4 d23 = *(const f32x4*)&Dsh[t][g * 4 + 2][0];
            f32x2 d0s = lo2(d01), d1s = hi2(d01), d2s = lo2(d23), d3s = hi2(d23);
            #pragma unroll
            for (int p = 0; p < 2; ++p) {
                const f32x2* e = p ? eH : eL;
                f32x2 q0 = fma2(e[0], d0s, one);
                f32x2 q1 = fma2(e[1], d1s, one);
                f32x2 q2 = fma2(e[2], d2s, one);
                f32x2 q3 = fma2(e[3], d3s, one);
                f32x2 q01 = q0 * q1, q23 = q2 * q3;
                f32x2 n1 = fma2(w0s, q1, w1s * q0);
                f32x2 n2 = fma2(w2s, q3, w3s * q2);
                f32x2 num = fma2(n1, q23, n2 * q01);
                f32x2 den = q01 * q23;
                f32x2 r; r.x = rcpf_(den.x); r.y = rcpf_(den.y);
                acc[t][p] = fma2(num, r, acc[t][p]);
            }
        }
    };

    for (int g = 0; g < 16; g += 2) {
        #pragma unroll
        for (int j = 0; j < 4; ++j) eB[j] = *(const f32x4*)&Eb[(size_t)((g + 1) * 4 + j) * S_];
        compute(eA, g);
        if (g + 2 < 16) {
            #pragma unroll
            for (int j = 0; j < 4; ++j) eA[j] = *(const f32x4*)&Eb[(size_t)((g + 2) * 4 + j) * S_];
        }
        compute(eB, g + 1);
    }

    float* Pd = (h == 0) ? P0 : (h == 1) ? P1 : (h == 2) ? P2 : P3;
    #pragma unroll
    for (int t = 0; t < 4; ++t) {
        f32x4 o = { acc[t][0].x, acc[t][0].y, acc[t][1].x, acc[t][1].y };
        *(f32x4*)&Pd[((size_t)b * T_ + t0 + t) * S_ + s0] = o;
    }
}

// ---------------------------------------------------------------------------
// Kernel 3: merge NP partials + softmax. block = one (b,t) row; 256 thr x 4 s.
// score' = -2*sum(P); softmax without max-subtraction (|score'| <= ~26, exp2
// args safe in fp32; normalization cancels the shift exactly).
// P0 lives in d_out; in-place read->write safe (each thread owns its s).
// ---------------------------------------------------------------------------
template<int NP>
__global__ __launch_bounds__(256)
void merge_softmax(const float* __restrict__ P1, const float* __restrict__ P2,
                   const float* __restrict__ P3, float* __restrict__ outp)
{
    const int row = blockIdx.x;
    const int tid = threadIdx.x;
    const int lane = tid & 63, wid = tid >> 6;
    __shared__ float red[4];

    float* o = outp + (size_t)row * S_;
    const int s4 = tid << 2;

    float4 a = *(const float4*)&o[s4];
    {
        float4 c = *(const float4*)&P1[(size_t)row * S_ + s4];
        a.x += c.x; a.y += c.y; a.z += c.z; a.w += c.w;
    }
    if (NP >= 4) {
        float4 c = *(const float4*)&P2[(size_t)row * S_ + s4];
        a.x += c.x; a.y += c.y; a.z += c.z; a.w += c.w;
        float4 e = *(const float4*)&P3[(size_t)row * S_ + s4];
        a.x += e.x; a.y += e.y; a.z += e.z; a.w += e.w;
    }
    float e0 = ex2(a.x * -K2F);
    float e1 = ex2(a.y * -K2F);
    float e2 = ex2(a.z * -K2F);
    float e3 = ex2(a.w * -K2F);

    float ssum = (e0 + e1) + (e2 + e3);
    #pragma unroll
    for (int off = 32; off > 0; off >>= 1) ssum += __shfl_xor(ssum, off, 64);
    if (lane == 0) red[wid] = ssum;
    __syncthreads();
    float tot = (red[0] + red[1]) + (red[2] + red[3]);
    float inv = 1.0f / tot;

    *(float4*)&o[s4] = make_float4(e0 * inv, e1 * inv, e2 * inv, e3 * inv);
}

// ---------------------------------------------------------------------------
// Fallback score kernel (round-7 scalar, AS=2) for small ws.
// ---------------------------------------------------------------------------
__global__ __launch_bounds__(512)
void score_partial2(const float* __restrict__ E, const float* __restrict__ D,
                    const float* __restrict__ Wv,
                    float* __restrict__ P0, float* __restrict__ P1)
{
    constexpr int ABLK = 128;
    constexpr int NG   = 32;

    const int tid = threadIdx.x;
    const int bid = blockIdx.x;
    const int b   = bid >> 7;
    const int rem = bid & 127;
    const int h   = rem & 1;
    const int t0  = (rem >> 1) * 4;
    const int abase = h * ABLK;

    __shared__ float Dsh[4][ABLK];
    __shared__ float Wsh[ABLK];

    if (tid < ABLK) {
        int r = tid / 32, c4 = (tid % 32) << 2;
        *(float4*)&Dsh[r][c4] = *(const float4*)&D[((size_t)b * T_ + t0 + r) * A_ + abase + c4];
    } else if (tid < ABLK + 32) {
        int c4 = (tid - ABLK) << 2;
        *(float4*)&Wsh[c4] = *(const float4*)&Wv[abase + c4];
    }
    __syncthreads();

    const int s0 = tid << 1;
    const float* Eb = E + ((size_t)b * A_ + abase) * S_ + s0;

    float accx[4] = {}, accy[4] = {};
    float2 evA[4], evB[4];

    #pragma unroll
    for (int j = 0; j < 4; ++j) evA[j] = *(const float2*)&Eb[(size_t)j * S_];

    auto compute = [&](const float2* ev, int g) {
        float4 w = *(const float4*)&Wsh[g * 4];
        #pragma unroll
        for (int t = 0; t < 4; ++t) {
            float4 d = *(const float4*)&Dsh[t][g * 4];
            {
                float q0 = fmaf(ev[0].x, d.x, 1.0f);
                float q1 = fmaf(ev[1].x, d.y, 1.0f);
                float q2 = fmaf(ev[2].x, d.z, 1.0f);
                float q3 = fmaf(ev[3].x, d.w, 1.0f);
                float q01 = q0 * q1, q23 = q2 * q3;
                float n1 = fmaf(w.x, q1, w.y * q0);
                float n2 = fmaf(w.z, q3, w.w * q2);
                float num = fmaf(n1, q23, n2 * q01);
                accx[t] = fmaf(num, rcpf_(q01 * q23), accx[t]);
            }
            {
                float q0 = fmaf(ev[0].y, d.x, 1.0f);
                float q1 = fmaf(ev[1].y, d.y, 1.0f);
                float q2 = fmaf(ev[2].y, d.z, 1.0f);
                float q3 = fmaf(ev[3].y, d.w, 1.0f);
                float q01 = q0 * q1, q23 = q2 * q3;
                float n1 = fmaf(w.x, q1, w.y * q0);
                float n2 = fmaf(w.z, q3, w.w * q2);
                float num = fmaf(n1, q23, n2 * q01);
                accy[t] = fmaf(num, rcpf_(q01 * q23), accy[t]);
            }
        }
    };

    for (int g = 0; g < NG; g += 2) {
        #pragma unroll
        for (int j = 0; j < 4; ++j) evB[j] = *(const float2*)&Eb[(size_t)((g + 1) * 4 + j) * S_];
        compute(evA, g);
        if (g + 2 < NG) {
            #pragma unroll
            for (int j = 0; j < 4; ++j) evA[j] = *(const float2*)&Eb[(size_t)((g + 2) * 4 + j) * S_];
        }
        compute(evB, g + 1);
    }

    float* Pd = h ? P1 : P0;
    #pragma unroll
    for (int t = 0; t < 4; ++t) {
        float2 o; o.x = accx[t]; o.y = accy[t];
        *(float2*)&Pd[((size_t)b * T_ + t0 + t) * S_ + s0] = o;
    }
}

// ---------------------------------------------------------------------------
extern "C" void kernel_launch(void* const* d_in, const int* in_sizes, int n_in,
                              void* d_out, int out_size, void* d_ws, size_t ws_size,
                              hipStream_t stream)
{
    const float* enc = (const float*)d_in[0];
    const float* dec = (const float*)d_in[1];
    const float* Wh  = (const float*)d_in[2];
    const float* bh  = (const float*)d_in[3];
    const float* Wsm = (const float*)d_in[4];
    const float* bs  = (const float*)d_in[5];
    const float* Wv  = (const float*)d_in[6];
    // d_in[7] (bv) intentionally unused: softmax is shift-invariant.

    char* ws = (char*)d_ws;
    float* Ebuf = (float*)ws;                                // [0,4MB)
    float* Dbuf = (float*)(ws + (4 << 20));                  // [4,5MB)
    unsigned short* wt = (unsigned short*)(ws + (5 << 20));  // [5,6MB)
    unsigned short* WhTh = wt;
    unsigned short* WhTl = wt + 131072;
    unsigned short* WsTh = wt + 262144;
    unsigned short* WsTl = wt + 393216;

    prep_w<<<256, 256, 0, stream>>>(Wh, Wsm, WhTh, WhTl, WsTh, WsTl);
    gemm_mfma<<<320, 256, 0, stream>>>(enc, dec, WhTh, WhTl, WsTh, WsTl,
                                       bh, bs, Ebuf, Dbuf);

    float* P0 = (float*)d_out;                               // partial 0 in-place
    if (ws_size >= (size_t)(18 << 20)) {
        float* P1 = (float*)(ws + (6 << 20));
        float* P2 = (float*)(ws + (10 << 20));
        float* P3 = (float*)(ws + (14 << 20));
        score_partial_pk<<<B_ * 256, 256, 0, stream>>>(Ebuf, Dbuf, Wv, P0, P1, P2, P3);
        merge_softmax<4><<<B_ * T_, 256, 0, stream>>>(P1, P2, P3, (float*)d_out);
    } else {
        float* P1 = (float*)(ws + (6 << 20));
        score_partial2<<<B_ * 128, 512, 0, stream>>>(Ebuf, Dbuf, Wv, P0, P1);
        merge_softmax<2><<<B_ * T_, 256, 0, stream>>>(P1, nullptr, nullptr, (float*)d_out);
    }
}